// Round 9
// baseline (153.456 us; speedup 1.0000x reference)
//
#include <hip/hip_runtime.h>

// Problem constants (from reference setup_inputs)
#define BB 64
#define NN 128
#define DD 128
#define AA 1000
#define NEG_INF (-9.0e15f)

typedef __attribute__((ext_vector_type(8))) short short8;   // 8 bf16 MFMA frag
typedef __attribute__((ext_vector_type(4))) float floatx4;  // MFMA C/D frag
typedef __attribute__((ext_vector_type(4))) unsigned int uintx4;

__device__ __forceinline__ float bflo(unsigned int u) { return __uint_as_float(u << 16); }
__device__ __forceinline__ float bfhi(unsigned int u) { return __uint_as_float(u & 0xffff0000u); }
// truncating fp32->bf16 pack (~2^-9 rel bias, fine vs 1.73 threshold)
__device__ __forceinline__ unsigned int packbf(float f0, float f1) {
  return (__float_as_uint(f0) >> 16) | (__float_as_uint(f1) & 0xffff0000u);
}
// round-to-nearest-even fp32->bf16
__device__ __forceinline__ unsigned short bf_rne(float f) {
  unsigned int u = __float_as_uint(f);
  return (unsigned short)((u + 0x7fffu + ((u >> 16) & 1u)) >> 16);
}
__device__ __forceinline__ unsigned int packbf_rne(float f0, float f1) {
  return (unsigned int)bf_rne(f0) | ((unsigned int)bf_rne(f1) << 16);
}
__device__ __forceinline__ short8 u2s(uintx4 v) {
  union { uintx4 u; short8 s; } x; x.u = v; return x.s;
}

// ---------------------------------------------------------------------------
// Single fused dispatch, 768 blocks: blockIdx%3<2 -> attention (512 blocks:
// batch b, 16-row i-tile); ==2 -> attr GEMM (256 blocks: 32-row tile).
// LDS union = 40960 B. __launch_bounds__(256,2) -> 256-VGPR budget: R7/R8's
// 64-VGPR allocations spilled ~37 dwords/thread to scratch (26-29 MB of extra
// HBM writes, latency-bound kernel). Occupancy settles at 3-4 blocks/CU.
// ---------------------------------------------------------------------------
struct AttnSmem {
  __align__(16) unsigned short Hs[NN * 128];   // 32768 B bf16 h[b] (swizzled)
  __align__(16) unsigned short W[16 * 128];    // 4096 B softmax weights
  __align__(16) unsigned short safb[4 * 256];  // 2048 B bf16 {0.6a | 0.4a}
  float wredM[4 * 16];                         // 256 B cross-wave max
  float wredS[4 * 16];                         // 256 B cross-wave sum
};  // 39424 B

struct AttrSmem {
  __align__(16) unsigned short ETs[2][DD * 64];  // 32768 B emb^T bf16 chunks
  __align__(16) unsigned short As2[2][32 * 64];  // 8192 B A bf16 chunks
};  // 40960 B

union FusedSmem { AttnSmem a; AttrSmem g; };     // 40960 B

__device__ __forceinline__ void attn_body(
    AttnSmem& s, const float* __restrict__ hidden,
    const int* __restrict__ adj, const float* __restrict__ amat,
    float* __restrict__ out0, int aid)
{
  const int t = threadIdx.x;
  const int L = t & 63, w = t >> 6;     // wave = j-quarter (QK) / d-quarter (PV)
  const int lr = L & 15, lq = L >> 4;   // MFMA lane coords
  const int b = aid >> 3;
  const int i0 = (aid & 7) * 16;

  // ---- prefetch adj (in flight under staging) ----
  const int* adjb = adj + ((size_t)b * NN + i0) * NN;
  int adjv[8];
  #pragma unroll
  for (int nt = 0; nt < 2; ++nt)
    #pragma unroll
    for (int r = 0; r < 4; ++r)
      adjv[nt * 4 + r] = adjb[(lq * 4 + r) * NN + w * 32 + nt * 16 + lr];

  // ---- stage Hs from fp32 hidden (convert in flight; swizzle c^(row&15)) ----
  const float* hb = hidden + (size_t)b * NN * DD;
  #pragma unroll
  for (int u = 0; u < 8; ++u) {
    int id = u * 256 + t;
    int r = id >> 4, c = id & 15;
    const float* src = hb + r * 128 + c * 8;
    float4 v0 = *reinterpret_cast<const float4*>(src);
    float4 v1 = *reinterpret_cast<const float4*>(src + 4);
    uintx4 o;
    o.x = packbf_rne(v0.x, v0.y); o.y = packbf_rne(v0.z, v0.w);
    o.z = packbf_rne(v1.x, v1.y); o.w = packbf_rne(v1.z, v1.w);
    *reinterpret_cast<uintx4*>(&s.Hs[r * 128 + ((c ^ (r & 15)) << 3)]) = o;
  }
  // ---- bf16 scale table: safb[k][d]=0.6a[d][k], safb[k][128+d]=0.4a[d][k] ----
  {
    float v1 = amat[t], v2 = amat[t + 256];
    int dI = t >> 2, k = t & 3;
    s.safb[k * 256 + dI]        = bf_rne(0.6f * v1);
    s.safb[k * 256 + 128 + dI]  = bf_rne(0.4f * v1);
    s.safb[k * 256 + 64 + dI]   = bf_rne(0.6f * v2);
    s.safb[k * 256 + 192 + dI]  = bf_rne(0.4f * v2);
  }
  __syncthreads();

  // ---- QK: S_k = (h.0.6a_k)h^T + (|h|.0.4a_k)|h|^T, K'=256, A-frags in
  //      registers. kt<4: plain half; kt>=4: abs half. ----
  floatx4 acc[4][2];
  #pragma unroll
  for (int k = 0; k < 4; ++k)
    #pragma unroll
    for (int nt = 0; nt < 2; ++nt) acc[k][nt] = floatx4{0.f, 0.f, 0.f, 0.f};

  #pragma unroll
  for (int kt = 0; kt < 8; ++kt) {
    const int cb = lq + 4 * (kt & 3);      // Hs d-chunk 0..15
    const int aoff = (kt >= 4) ? 128 : 0;  // safb half select
    // A-side: h chunk for query row i0+lr ((i0+lr)&15 == lr)
    uintx4 ha = *reinterpret_cast<const uintx4*>(
        &s.Hs[(i0 + lr) * 128 + ((cb ^ lr) << 3)]);
    if (kt >= 4) {
      ha.x &= 0x7fff7fffu; ha.y &= 0x7fff7fffu;
      ha.z &= 0x7fff7fffu; ha.w &= 0x7fff7fffu;
    }
    const float h0 = bflo(ha.x), h1 = bfhi(ha.x), h2 = bflo(ha.y), h3 = bfhi(ha.y);
    const float h4 = bflo(ha.z), h5 = bfhi(ha.z), h6 = bflo(ha.w), h7 = bfhi(ha.w);
    short8 afr[4];
    #pragma unroll
    for (int k = 0; k < 4; ++k) {
      uintx4 sv = *reinterpret_cast<const uintx4*>(&s.safb[k * 256 + aoff + cb * 8]);
      uintx4 o;
      o.x = packbf(h0 * bflo(sv.x), h1 * bfhi(sv.x));
      o.y = packbf(h2 * bflo(sv.y), h3 * bfhi(sv.y));
      o.z = packbf(h4 * bflo(sv.z), h5 * bfhi(sv.z));
      o.w = packbf(h6 * bflo(sv.w), h7 * bfhi(sv.w));
      afr[k] = u2s(o);
    }
    // B-side: key rows (abs-masked for kt>=4)
    short8 bfr[2];
    #pragma unroll
    for (int nt = 0; nt < 2; ++nt) {
      int jrow = w * 32 + nt * 16 + lr;
      uintx4 hv = *reinterpret_cast<const uintx4*>(
          &s.Hs[jrow * 128 + ((cb ^ (jrow & 15)) << 3)]);
      if (kt >= 4) {
        hv.x &= 0x7fff7fffu; hv.y &= 0x7fff7fffu;
        hv.z &= 0x7fff7fffu; hv.w &= 0x7fff7fffu;
      }
      bfr[nt] = u2s(hv);
    }
    #pragma unroll
    for (int k = 0; k < 4; ++k)
      #pragma unroll
      for (int nt = 0; nt < 2; ++nt)
        acc[k][nt] = __builtin_amdgcn_mfma_f32_16x16x32_bf16(
            afr[k], bfr[nt], acc[k][nt], 0, 0, 0);
  }

  // ---- in-register adj selection; C/D: col=lane&15, row=(lane>>4)*4+reg ----
  float al[2][4];
  #pragma unroll
  for (int nt = 0; nt < 2; ++nt)
    #pragma unroll
    for (int r = 0; r < 4; ++r) {
      int ad = adjv[nt * 4 + r];
      float v = NEG_INF;
      v = (ad == 1) ? acc[0][nt][r] : v;
      v = (ad == 2) ? acc[1][nt][r] : v;
      v = (ad == 3) ? acc[2][nt][r] : v;
      v = (ad == 4) ? acc[3][nt][r] : v;
      al[nt][r] = v;
    }

  // ---- shuffle softmax: rows i=lq*4+r spread over lr(16) x nt(2) x w(4) ----
  float mr[4];
  #pragma unroll
  for (int r = 0; r < 4; ++r) mr[r] = fmaxf(al[0][r], al[1][r]);
  #pragma unroll
  for (int off = 1; off < 16; off <<= 1)
    #pragma unroll
    for (int r = 0; r < 4; ++r) mr[r] = fmaxf(mr[r], __shfl_xor(mr[r], off, 64));
  if (lr == 0)
    #pragma unroll
    for (int r = 0; r < 4; ++r) s.wredM[w * 16 + lq * 4 + r] = mr[r];
  __syncthreads();

  float ex[2][4], sr[4];
  #pragma unroll
  for (int r = 0; r < 4; ++r) {
    int i = lq * 4 + r;
    float m = fmaxf(fmaxf(s.wredM[i], s.wredM[16 + i]),
                    fmaxf(s.wredM[32 + i], s.wredM[48 + i]));
    // all-masked row: al-m == 0 -> uniform weights (matches jax); clamp guards exp
    ex[0][r] = __expf(fmaxf(al[0][r] - m, -80.f));
    ex[1][r] = __expf(fmaxf(al[1][r] - m, -80.f));
    sr[r] = ex[0][r] + ex[1][r];
  }
  #pragma unroll
  for (int off = 1; off < 16; off <<= 1)
    #pragma unroll
    for (int r = 0; r < 4; ++r) sr[r] += __shfl_xor(sr[r], off, 64);
  if (lr == 0)
    #pragma unroll
    for (int r = 0; r < 4; ++r) s.wredS[w * 16 + lq * 4 + r] = sr[r];
  __syncthreads();

  #pragma unroll
  for (int nt = 0; nt < 2; ++nt)
    #pragma unroll
    for (int r = 0; r < 4; ++r) {
      int i = lq * 4 + r;
      float ss = s.wredS[i] + s.wredS[16 + i] + s.wredS[32 + i] + s.wredS[48 + i];
      int j = w * 32 + nt * 16 + lr;
      s.W[i * 128 + (((j >> 3) ^ i) << 3) + (j & 7)] = bf_rne(ex[nt][r] / ss);
    }
  __syncthreads();

  // ---- PV: out[i][d] = sum_j W[i,j] h[j,d]; B-frags = Hs column u16 reads ----
  floatx4 oacc[2];
  oacc[0] = floatx4{0.f, 0.f, 0.f, 0.f};
  oacc[1] = floatx4{0.f, 0.f, 0.f, 0.f};
  #pragma unroll
  for (int kt = 0; kt < 4; ++kt) {
    int cw = lq + 4 * kt;
    short8 wf = *reinterpret_cast<const short8*>(
        &s.W[lr * 128 + ((cw ^ lr) << 3)]);
    #pragma unroll
    for (int nt = 0; nt < 2; ++nt) {
      int d = w * 32 + nt * 16 + lr;
      int sw = d >> 3, dl = d & 7;
      unsigned int rr[8];
      #pragma unroll
      for (int e = 0; e < 8; ++e) {
        int j = kt * 32 + lq * 8 + e;
        rr[e] = s.Hs[j * 128 + ((sw ^ (j & 15)) << 3) + dl];
      }
      uintx4 uu;
      uu.x = rr[0] | (rr[1] << 16); uu.y = rr[2] | (rr[3] << 16);
      uu.z = rr[4] | (rr[5] << 16); uu.w = rr[6] | (rr[7] << 16);
      oacc[nt] = __builtin_amdgcn_mfma_f32_16x16x32_bf16(wf, u2s(uu), oacc[nt], 0, 0, 0);
    }
  }
  float* ob = out0 + ((size_t)b * NN + i0) * DD;
  #pragma unroll
  for (int nt = 0; nt < 2; ++nt)
    #pragma unroll
    for (int r = 0; r < 4; ++r)
      ob[(lq * 4 + r) * DD + w * 32 + nt * 16 + lr] = oacc[nt][r];
}

__device__ __forceinline__ void attr_body(
    AttrSmem& s, const float* __restrict__ Aattr,
    const float* __restrict__ emb, float* __restrict__ out1, int gid)
{
  const int t = threadIdx.x;
  const int L = t & 63, w = t >> 6;
  const int lr = L & 15, lq = L >> 4;
  const int r0 = gid * 32;

  const int ar = t >> 3, ak = (t & 7) * 8, ac = t & 7;  // A fetch coords
  const int cq = t & 31, kg = t >> 5;                   // emb fetch coords

  // 1-iteration-ahead prefetch of BOTH streams (registers are no longer
  // scarce at the 256-VGPR budget; R8's JIT emb staging put a global-load
  // latency inside every iteration and regressed).
  float4 pa0, pa1, pe[8];

  auto fetch = [&](int it) {
    int kb = it * 64;
    int k4 = kb + ak;
    float4 z = {0.f, 0.f, 0.f, 0.f};
    pa0 = (k4 < AA) ? *reinterpret_cast<const float4*>(Aattr + (size_t)(r0 + ar) * AA + k4) : z;
    pa1 = (k4 + 4 < AA) ? *reinterpret_cast<const float4*>(Aattr + (size_t)(r0 + ar) * AA + k4 + 4) : z;
    #pragma unroll
    for (int q = 0; q < 8; ++q) {
      int k = kb + kg * 8 + q;
      pe[q] = (k < AA) ? *reinterpret_cast<const float4*>(emb + (size_t)k * 128 + cq * 4) : z;
    }
  };
  auto stage = [&](int buf) {
    uintx4 o;
    o.x = packbf(pa0.x, pa0.y); o.y = packbf(pa0.z, pa0.w);
    o.z = packbf(pa1.x, pa1.y); o.w = packbf(pa1.z, pa1.w);
    *reinterpret_cast<uintx4*>(&s.As2[buf][ar * 64 + ((ac ^ (ar & 7)) << 3)]) = o;
    // emb transpose-in-LDS. Swizzle (c ^ (c>>2)) & 7 is a bijection across
    // the 8 lane-groups -> store is bank-conflict-free (old kg^(c&7) mapped a
    // wave onto only 2 bank-groups: the R7/R8 1.9-4.0M conflict source).
    const float* pf = reinterpret_cast<const float*>(pe);
    #pragma unroll
    for (int cc = 0; cc < 4; ++cc) {
      int c = cq * 4 + cc;
      int swz = (kg ^ ((c ^ (c >> 2)) & 7));
      uintx4 e;
      e.x = packbf(pf[0 * 4 + cc], pf[1 * 4 + cc]);
      e.y = packbf(pf[2 * 4 + cc], pf[3 * 4 + cc]);
      e.z = packbf(pf[4 * 4 + cc], pf[5 * 4 + cc]);
      e.w = packbf(pf[6 * 4 + cc], pf[7 * 4 + cc]);
      *reinterpret_cast<uintx4*>(&s.ETs[buf][c * 64 + (swz << 3)]) = e;
    }
  };

  floatx4 acc[2][2];
  #pragma unroll
  for (int mt = 0; mt < 2; ++mt)
    #pragma unroll
    for (int nt = 0; nt < 2; ++nt) acc[mt][nt] = floatx4{0.f, 0.f, 0.f, 0.f};

  fetch(0);
  for (int it = 0; it < 16; ++it) {
    stage(it & 1);
    __syncthreads();
    if (it < 15) fetch(it + 1);  // overlaps compute below
    #pragma unroll
    for (int ks = 0; ks < 2; ++ks) {
      int c = lq + 4 * ks;
      short8 af[2], bf[2];
      #pragma unroll
      for (int mt = 0; mt < 2; ++mt) {
        int row = mt * 16 + lr;
        af[mt] = *reinterpret_cast<const short8*>(
            &s.As2[it & 1][row * 64 + ((c ^ (row & 7)) << 3)]);
      }
      #pragma unroll
      for (int nt = 0; nt < 2; ++nt) {
        int n = w * 32 + nt * 16 + lr;
        int swz = (c ^ ((n ^ (n >> 2)) & 7));
        bf[nt] = *reinterpret_cast<const short8*>(
            &s.ETs[it & 1][n * 64 + (swz << 3)]);
      }
      #pragma unroll
      for (int mt = 0; mt < 2; ++mt)
        #pragma unroll
        for (int nt = 0; nt < 2; ++nt)
          acc[mt][nt] = __builtin_amdgcn_mfma_f32_16x16x32_bf16(
              af[mt], bf[nt], acc[mt][nt], 0, 0, 0);
    }
    // single barrier/iter: next iter stages the OTHER buffer
  }

  float* ob = out1 + (size_t)r0 * DD;
  #pragma unroll
  for (int mt = 0; mt < 2; ++mt)
    #pragma unroll
    for (int nt = 0; nt < 2; ++nt)
      #pragma unroll
      for (int r = 0; r < 4; ++r)
        ob[(mt * 16 + lq * 4 + r) * DD + w * 32 + nt * 16 + lr] = acc[mt][nt][r];
}

// (256,2): min 2 waves/EU -> 256-VGPR register budget -> no scratch spills.
// Hardware occupancy then settles via LDS/VGPR at 3-4 blocks/CU.
__global__ __launch_bounds__(256, 2) void fused_kernel(
    const float* __restrict__ hidden, const int* __restrict__ adj,
    const float* __restrict__ amat, const float* __restrict__ Aattr,
    const float* __restrict__ emb,
    float* __restrict__ out0, float* __restrict__ out1)
{
  __shared__ FusedSmem sm;
  const int q3 = blockIdx.x / 3;
  const int r3 = blockIdx.x % 3;
  if (r3 == 2) attr_body(sm.g, Aattr, emb, out1, q3);                 // 256 blocks
  else         attn_body(sm.a, hidden, adj, amat, out0, q3 * 2 + r3); // 512 blocks
}

extern "C" void kernel_launch(void* const* d_in, const int* in_sizes, int n_in,
                              void* d_out, int out_size, void* d_ws, size_t ws_size,
                              hipStream_t stream) {
  const float* hidden = (const float*)d_in[0];  // [64,128,128] fp32
  const int*   adj    = (const int*)d_in[1];    // [64,128,128] int32
  const float* amat   = (const float*)d_in[2];  // [128,4] fp32
  const float* Aattr  = (const float*)d_in[3];  // [64,128,1000] fp32
  const float* emb    = (const float*)d_in[4];  // [1000,128] fp32

  float* out0 = (float*)d_out;                  // output    [64,128,128] fp32
  float* out1 = out0 + (size_t)BB * NN * DD;    // attr_sess [64,128,128] fp32

  fused_kernel<<<768, 256, 0, stream>>>(hidden, adj, amat, Aattr, emb, out0, out1);
}

// Round 10
// 106.552 us; speedup vs baseline: 1.4402x; 1.4402x over previous
//
#include <hip/hip_runtime.h>

// Problem constants (from reference setup_inputs)
#define BB 64
#define NN 128
#define DD 128
#define AA 1000
#define KPAD 1024
#define NEG_INF (-9.0e15f)

typedef __attribute__((ext_vector_type(8))) short short8;   // 8 bf16 MFMA frag
typedef __attribute__((ext_vector_type(4))) float floatx4;  // MFMA C/D frag
typedef __attribute__((ext_vector_type(4))) unsigned int uintx4;
typedef __attribute__((ext_vector_type(2))) unsigned int uintx2;

__device__ __forceinline__ float bflo(unsigned int u) { return __uint_as_float(u << 16); }
__device__ __forceinline__ float bfhi(unsigned int u) { return __uint_as_float(u & 0xffff0000u); }
// truncating fp32->bf16 pack (cheap; ~2^-9 rel bias, fine vs 1.73 threshold)
__device__ __forceinline__ unsigned int packbf(float f0, float f1) {
  return (__float_as_uint(f0) >> 16) | (__float_as_uint(f1) & 0xffff0000u);
}
// round-to-nearest-even fp32->bf16
__device__ __forceinline__ unsigned short bf_rne(float f) {
  unsigned int u = __float_as_uint(f);
  return (unsigned short)((u + 0x7fffu + ((u >> 16) & 1u)) >> 16);
}
__device__ __forceinline__ unsigned int packbf_rne(float f0, float f1) {
  return (unsigned int)bf_rne(f0) | ((unsigned int)bf_rne(f1) << 16);
}
__device__ __forceinline__ short8 u2s(uintx4 v) {
  union { uintx4 u; short8 s; } x; x.u = v; return x.s;
}

// ---------------------------------------------------------------------------
// Prep (192 blocks x 256): blocks 0..63 -> HTg[b][d][i] = bf16(h[b]^T);
// blocks 64..191 -> ET[c][k] = bf16(emb[k][c]), k zero-padded to 1024.
// (attn converts fp32 h in-kernel; HTg feeds the PV B-fragments.)
// ---------------------------------------------------------------------------
__global__ __launch_bounds__(256) void prep_kernel(
    const float* __restrict__ hidden, const float* __restrict__ emb,
    unsigned short* __restrict__ ET, unsigned short* __restrict__ HTg)
{
  const int t = threadIdx.x;
  const int bid = blockIdx.x;
  if (bid < BB) {
    __shared__ float hsf[NN * 129];
    const float* hb = hidden + (size_t)bid * NN * DD;
    #pragma unroll
    for (int u = 0; u < 16; ++u) {
      int e = u * 1024 + t * 4;
      float4 v = *reinterpret_cast<const float4*>(hb + e);
      int r = e >> 7, c = e & 127;
      float* d = &hsf[r * 129 + c];
      d[0] = v.x; d[1] = v.y; d[2] = v.z; d[3] = v.w;
    }
    __syncthreads();
    unsigned short* ht16 = HTg + (size_t)bid * NN * DD;
    #pragma unroll
    for (int u = 0; u < 8; ++u) {  // transpose via LDS columns
      int e = u * 2048 + t * 8;
      int dI = e >> 7, il = e & 127;
      float x[8];
      #pragma unroll
      for (int j = 0; j < 8; ++j) x[j] = hsf[(il + j) * 129 + dI];
      uintx4 o;
      o.x = packbf_rne(x[0], x[1]); o.y = packbf_rne(x[2], x[3]);
      o.z = packbf_rne(x[4], x[5]); o.w = packbf_rne(x[6], x[7]);
      *reinterpret_cast<uintx4*>(ht16 + e) = o;
    }
  } else {
    int c = bid - BB;       // 0..127
    int k0 = t * 4;
    float x[4];
    #pragma unroll
    for (int j = 0; j < 4; ++j) {
      int k = k0 + j;
      x[j] = (k < AA) ? emb[(size_t)k * DD + c] : 0.f;
    }
    uintx2 o;
    o.x = packbf_rne(x[0], x[1]);
    o.y = packbf_rne(x[2], x[3]);
    *reinterpret_cast<uintx2*>(ET + (size_t)c * KPAD + k0) = o;
  }
}

// ---------------------------------------------------------------------------
// Fused kernel: blocks 0..511 = attention (b, 16-row i-tile); 512..767 = attr
// GEMM (32-row tile). Shared-memory union keeps LDS at ~53 KB.
// LDS-As QK structure: As built ONCE with full 256-thread parallelism, so the
// QK inner loop is pure ds_read_b128 + MFMA (no VALU repack on the critical
// path — the register-As variants of R6..R9 all regressed on that chain).
// ---------------------------------------------------------------------------
struct AttnSmem {
  __align__(16) unsigned short Hs[NN * 128];        // 32768 B bf16 h (swizzled)
  union {
    __align__(16) unsigned short As[4 * 16 * 256];  // 16384 B (QK phase only)
    struct {
      __align__(16) float Sa[16 * 129];             // 8256 B (post-QK)
      __align__(16) unsigned short W[16 * 128];     // 4096 B (softmax out)
    } sw;
  } u2;
  __align__(16) float saf[4 * 256];                 // 4096 B scale table
};  // 53248 B

#define BK 64
struct AttrSmem {
  __align__(16) unsigned short ETs[2][DD * BK];     // 32768 B
  __align__(16) unsigned short As2[2][32 * BK];     // 8192 B
};  // 40960 B

union FusedSmem { AttnSmem a; AttrSmem g; };        // 53248 B

__device__ __forceinline__ void attn_body(
    AttnSmem& s, const float* __restrict__ hidden,
    const int* __restrict__ adj, const float* __restrict__ amat,
    const unsigned short* __restrict__ HTg, float* __restrict__ out0)
{
  const int t = threadIdx.x;
  const int L = t & 63, w = t >> 6;     // wave w = j-quarter / d-quarter
  const int lr = L & 15, lq = L >> 4;   // MFMA lane coords
  const int b = blockIdx.x >> 3;
  const int i0 = (blockIdx.x & 7) * 16;

  // ---- prefetch adj (in flight under staging) ----
  const int* adjb = adj + ((size_t)b * NN + i0) * NN;
  int adjv[8];
  #pragma unroll
  for (int nt = 0; nt < 2; ++nt)
    #pragma unroll
    for (int r = 0; r < 4; ++r)
      adjv[nt * 4 + r] = adjb[(lq * 4 + r) * NN + w * 32 + nt * 16 + lr];

  // ---- stage Hs from fp32 hidden (convert in flight; swizzle c^(row&15)) ----
  const float* hb = hidden + (size_t)b * NN * DD;
  #pragma unroll
  for (int u = 0; u < 8; ++u) {
    int id = u * 256 + t;
    int r = id >> 4, c = id & 15;
    const float* src = hb + r * 128 + c * 8;
    float4 v0 = *reinterpret_cast<const float4*>(src);
    float4 v1 = *reinterpret_cast<const float4*>(src + 4);
    uintx4 o;
    o.x = packbf_rne(v0.x, v0.y); o.y = packbf_rne(v0.z, v0.w);
    o.z = packbf_rne(v1.x, v1.y); o.w = packbf_rne(v1.z, v1.w);
    *reinterpret_cast<uintx4*>(&s.Hs[r * 128 + ((c ^ (r & 15)) << 3)]) = o;
  }
  // ---- scale table: saf[k][d]=0.6*a[d][k], saf[k][128+d]=0.4*a[d][k] ----
  {
    float v1 = amat[t], v2 = amat[t + 256];
    int dI = t >> 2, k = t & 3;
    s.saf[k * 256 + dI] = 0.6f * v1;
    s.saf[k * 256 + 128 + dI] = 0.4f * v1;
    s.saf[k * 256 + 64 + dI] = 0.6f * v2;
    s.saf[k * 256 + 192 + dI] = 0.4f * v2;
  }
  __syncthreads();

  // ---- build As[k][i][d'] (d'<128: h*0.6a_k ; d'>=128: |h|*0.4a_k) ----
  #pragma unroll
  for (int u = 0; u < 8; ++u) {
    int id = u * 256 + t;
    int k = id >> 9, ii = (id >> 5) & 15, c = id & 31;
    int srow = i0 + ii;
    int dchunk = c & 15;
    uintx4 hv = *reinterpret_cast<const uintx4*>(
        &s.Hs[srow * 128 + ((dchunk ^ (srow & 15)) << 3)]);
    if (c & 16) {
      hv.x &= 0x7fff7fffu; hv.y &= 0x7fff7fffu;
      hv.z &= 0x7fff7fffu; hv.w &= 0x7fff7fffu;
    }
    const float* sf = &s.saf[k * 256 + c * 8];
    uintx4 o;
    o.x = packbf(bflo(hv.x) * sf[0], bfhi(hv.x) * sf[1]);
    o.y = packbf(bflo(hv.y) * sf[2], bfhi(hv.y) * sf[3]);
    o.z = packbf(bflo(hv.z) * sf[4], bfhi(hv.z) * sf[5]);
    o.w = packbf(bflo(hv.w) * sf[6], bfhi(hv.w) * sf[7]);
    *reinterpret_cast<uintx4*>(&s.u2.As[k * 4096 + ii * 256 + ((c ^ ii) << 3)]) = o;
  }
  __syncthreads();

  // ---- QK: all 4 edge-type scores in one K'=256 GEMM, 8 MFMA/step ----
  floatx4 acc[4][2];
  #pragma unroll
  for (int k = 0; k < 4; ++k)
    #pragma unroll
    for (int nt = 0; nt < 2; ++nt) acc[k][nt] = floatx4{0.f, 0.f, 0.f, 0.f};

  #pragma unroll
  for (int kt = 0; kt < 8; ++kt) {
    int ca = lq + 4 * kt;
    short8 afr[4];
    #pragma unroll
    for (int k = 0; k < 4; ++k)
      afr[k] = *reinterpret_cast<const short8*>(
          &s.u2.As[k * 4096 + lr * 256 + ((ca ^ lr) << 3)]);
    int cb = lq + 4 * (kt & 3);
    short8 bfr[2];
    #pragma unroll
    for (int nt = 0; nt < 2; ++nt) {
      int jrow = w * 32 + nt * 16 + lr;
      uintx4 hv = *reinterpret_cast<const uintx4*>(
          &s.Hs[jrow * 128 + ((cb ^ (jrow & 15)) << 3)]);
      if (kt >= 4) {
        hv.x &= 0x7fff7fffu; hv.y &= 0x7fff7fffu;
        hv.z &= 0x7fff7fffu; hv.w &= 0x7fff7fffu;
      }
      bfr[nt] = u2s(hv);
    }
    #pragma unroll
    for (int k = 0; k < 4; ++k)
      #pragma unroll
      for (int nt = 0; nt < 2; ++nt)
        acc[k][nt] = __builtin_amdgcn_mfma_f32_16x16x32_bf16(
            afr[k], bfr[nt], acc[k][nt], 0, 0, 0);
  }
  __syncthreads();  // all As reads done; Sa/W may now overlay As

  // ---- prefetch PV B-frags from HTg (hides under selection/softmax) ----
  short8 pvb[2][4];
  const unsigned short* ht = HTg + (size_t)b * NN * DD;
  #pragma unroll
  for (int nt = 0; nt < 2; ++nt)
    #pragma unroll
    for (int kt = 0; kt < 4; ++kt) {
      int dI = w * 32 + nt * 16 + lr;
      pvb[nt][kt] = *reinterpret_cast<const short8*>(ht + dI * 128 + kt * 32 + lq * 8);
    }

  // ---- in-register adj selection; C/D: col=lane&15, row=(lane>>4)*4+reg ----
  #pragma unroll
  for (int nt = 0; nt < 2; ++nt)
    #pragma unroll
    for (int r = 0; r < 4; ++r) {
      int ii = lq * 4 + r;
      int j = w * 32 + nt * 16 + lr;
      int ad = adjv[nt * 4 + r];
      float al = NEG_INF;
      al = (ad == 1) ? acc[0][nt][r] : al;
      al = (ad == 2) ? acc[1][nt][r] : al;
      al = (ad == 3) ? acc[2][nt][r] : al;
      al = (ad == 4) ? acc[3][nt][r] : al;
      s.u2.sw.Sa[ii * 129 + j] = al;
    }
  __syncthreads();

  // ---- softmax: one full row per wave (lane holds j=L and j=L+64) ----
  #pragma unroll
  for (int p = 0; p < 4; ++p) {
    int ii = w * 4 + p;
    float a1 = s.u2.sw.Sa[ii * 129 + L];
    float a2 = s.u2.sw.Sa[ii * 129 + 64 + L];
    float m = fmaxf(a1, a2);
    #pragma unroll
    for (int off = 32; off > 0; off >>= 1) m = fmaxf(m, __shfl_xor(m, off, 64));
    // all-masked row: a-m==0 -> uniform (matches jax); clamp guards exp
    float e1 = __expf(fmaxf(a1 - m, -80.f));
    float e2 = __expf(fmaxf(a2 - m, -80.f));
    float ss = e1 + e2;
    #pragma unroll
    for (int off = 32; off > 0; off >>= 1) ss += __shfl_xor(ss, off, 64);
    float inv = 1.f / ss;
    int j2 = L + 64;
    s.u2.sw.W[ii * 128 + (((L >> 3) ^ ii) << 3) + (L & 7)] = bf_rne(e1 * inv);
    s.u2.sw.W[ii * 128 + (((j2 >> 3) ^ ii) << 3) + (j2 & 7)] = bf_rne(e2 * inv);
  }
  __syncthreads();

  // ---- PV: out[i][d] = sum_j W[i,j] * h[j,d] (B from HTg prefetch) ----
  floatx4 oacc[2];
  oacc[0] = floatx4{0.f, 0.f, 0.f, 0.f};
  oacc[1] = floatx4{0.f, 0.f, 0.f, 0.f};
  #pragma unroll
  for (int kt = 0; kt < 4; ++kt) {
    int c = lq + 4 * kt;
    short8 wf = *reinterpret_cast<const short8*>(
        &s.u2.sw.W[lr * 128 + ((c ^ lr) << 3)]);
    #pragma unroll
    for (int nt = 0; nt < 2; ++nt)
      oacc[nt] = __builtin_amdgcn_mfma_f32_16x16x32_bf16(
          wf, pvb[nt][kt], oacc[nt], 0, 0, 0);
  }
  float* ob = out0 + ((size_t)b * NN + i0) * DD;
  #pragma unroll
  for (int nt = 0; nt < 2; ++nt)
    #pragma unroll
    for (int r = 0; r < 4; ++r)
      ob[(lq * 4 + r) * DD + w * 32 + nt * 16 + lr] = oacc[nt][r];
}

__device__ __forceinline__ void attr_body(
    AttrSmem& s, const float* __restrict__ Aattr,
    const unsigned short* __restrict__ ET, float* __restrict__ out1)
{
  const int t = threadIdx.x;
  const int L = t & 63, w = t >> 6;
  const int lr = L & 15, lq = L >> 4;
  const int r0 = (blockIdx.x - 512) * 32;

  float4 pa0, pa1;
  uintx4 pe[4];
  const int ar = t >> 3, ak = (t & 7) * 8;
  const int ec = t >> 1, ej0 = (t & 1) * 4;

  auto fetch = [&](int it) {
    int kb = it * BK;
    int k4 = kb + ak;
    float4 z = {0.f, 0.f, 0.f, 0.f};
    pa0 = (k4 < AA) ? *reinterpret_cast<const float4*>(Aattr + (size_t)(r0 + ar) * AA + k4) : z;
    pa1 = (k4 + 4 < AA) ? *reinterpret_cast<const float4*>(Aattr + (size_t)(r0 + ar) * AA + k4 + 4) : z;
    #pragma unroll
    for (int q = 0; q < 4; ++q)
      pe[q] = *reinterpret_cast<const uintx4*>(ET + (size_t)ec * KPAD + kb + (ej0 + q) * 8);
  };
  auto stage = [&](int buf) {
    uintx4 o;
    o.x = packbf(pa0.x, pa0.y); o.y = packbf(pa0.z, pa0.w);
    o.z = packbf(pa1.x, pa1.y); o.w = packbf(pa1.z, pa1.w);
    int ac = t & 7;
    *reinterpret_cast<uintx4*>(&s.As2[buf][ar * BK + ((ac ^ (ar & 7)) << 3)]) = o;
    #pragma unroll
    for (int q = 0; q < 4; ++q)
      *reinterpret_cast<uintx4*>(&s.ETs[buf][ec * BK + (((ej0 + q) ^ (ec & 7)) << 3)]) = pe[q];
  };

  floatx4 acc[2][2];
  #pragma unroll
  for (int mt = 0; mt < 2; ++mt)
    #pragma unroll
    for (int nt = 0; nt < 2; ++nt) acc[mt][nt] = floatx4{0.f, 0.f, 0.f, 0.f};

  fetch(0);
  for (int it = 0; it < 16; ++it) {
    stage(it & 1);
    __syncthreads();
    if (it < 15) fetch(it + 1);  // overlaps compute below
    #pragma unroll
    for (int ks = 0; ks < 2; ++ks) {
      int c = lq + 4 * ks;
      short8 af[2], bf[2];
      #pragma unroll
      for (int mt = 0; mt < 2; ++mt) {
        int row = mt * 16 + lr;
        af[mt] = *reinterpret_cast<const short8*>(
            &s.As2[it & 1][row * BK + ((c ^ (row & 7)) << 3)]);
      }
      #pragma unroll
      for (int nt = 0; nt < 2; ++nt) {
        int n = w * 32 + nt * 16 + lr;
        bf[nt] = *reinterpret_cast<const short8*>(
            &s.ETs[it & 1][n * BK + ((c ^ (n & 7)) << 3)]);
      }
      #pragma unroll
      for (int mt = 0; mt < 2; ++mt)
        #pragma unroll
        for (int nt = 0; nt < 2; ++nt)
          acc[mt][nt] = __builtin_amdgcn_mfma_f32_16x16x32_bf16(
              af[mt], bf[nt], acc[mt][nt], 0, 0, 0);
    }
    // no 2nd barrier: next iter stages the OTHER buffer (2-stage pipeline)
  }

  float* ob = out1 + (size_t)r0 * DD;
  #pragma unroll
  for (int mt = 0; mt < 2; ++mt)
    #pragma unroll
    for (int nt = 0; nt < 2; ++nt)
      #pragma unroll
      for (int r = 0; r < 4; ++r)
        ob[(mt * 16 + lq * 4 + r) * DD + w * 32 + nt * 16 + lr] = acc[mt][nt][r];
}

__global__ __launch_bounds__(256, 3) void fused_kernel(
    const float* __restrict__ hidden, const int* __restrict__ adj,
    const float* __restrict__ amat, const float* __restrict__ Aattr,
    const unsigned short* __restrict__ ET, const unsigned short* __restrict__ HTg,
    float* __restrict__ out0, float* __restrict__ out1)
{
  __shared__ FusedSmem sm;
  if (blockIdx.x < 512) attn_body(sm.a, hidden, adj, amat, HTg, out0);
  else                  attr_body(sm.g, Aattr, ET, out1);
}

extern "C" void kernel_launch(void* const* d_in, const int* in_sizes, int n_in,
                              void* d_out, int out_size, void* d_ws, size_t ws_size,
                              hipStream_t stream) {
  const float* hidden = (const float*)d_in[0];  // [64,128,128] fp32
  const int*   adj    = (const int*)d_in[1];    // [64,128,128] int32
  const float* amat   = (const float*)d_in[2];  // [128,4] fp32
  const float* Aattr  = (const float*)d_in[3];  // [64,128,1000] fp32
  const float* emb    = (const float*)d_in[4];  // [1000,128] fp32

  float* out0 = (float*)d_out;                  // output    [64,128,128] fp32
  float* out1 = out0 + (size_t)BB * NN * DD;    // attr_sess [64,128,128] fp32

  // d_ws layout (rebuilt every call): bf16 operand copies
  unsigned short* ET  = (unsigned short*)d_ws;      // [128][1024]
  unsigned short* HTg = ET + (size_t)DD * KPAD;     // [64][128][128] h^T

  prep_kernel<<<BB + DD, 256, 0, stream>>>(hidden, emb, ET, HTg);
  fused_kernel<<<768, 256, 0, stream>>>(hidden, adj, amat, Aattr, ET, HTg,
                                        out0, out1);
}